// Round 4
// baseline (820.298 us; speedup 1.0000x reference)
//
#include <hip/hip_runtime.h>
#include <math.h>

#define W 128
#define H 128
#define HW 16384
#define CIN 96
#define COUT 96
#define BATCH 16

typedef __bf16 bf16x8 __attribute__((ext_vector_type(8)));
typedef float f32x4 __attribute__((ext_vector_type(4)));

typedef const unsigned int __attribute__((address_space(1))) gu32;
typedef unsigned int __attribute__((address_space(3))) lu32;
// async gather-to-LDS: per-lane global addr, wave-uniform LDS base + lane*4
#define GLDS(g, l) __builtin_amdgcn_global_load_lds((gu32*)(g), (lu32*)(l), 4, 0, 0)

// ---------------------------------------------------------------------------
// Weight prep (unchanged):
//   wAT[c][kk][28] f32: o-contiguous (o<18: offset_w, 18..26: mask_w, 27 pad)
//   wBT_bf[tap][o][c] bf16: main weight, c-contiguous per output row.
// ---------------------------------------------------------------------------
__global__ void prep_weights(const float* __restrict__ weight,
                             const float* __restrict__ offset_w,
                             const float* __restrict__ mask_w,
                             float* __restrict__ wAT,
                             __bf16* __restrict__ wBT_bf) {
  int idx = blockIdx.x * blockDim.x + threadIdx.x;
  const int nA = CIN * 9 * 28;
  if (idx < nA) {
    int o = idx % 28;
    int rest = idx / 28;
    int kk = rest % 9;
    int c = rest / 9;
    float v = 0.f;
    if (o < 18)      v = offset_w[(o * CIN + c) * 9 + kk];
    else if (o < 27) v = mask_w[((o - 18) * CIN + c) * 9 + kk];
    wAT[idx] = v;
  } else {
    int j = idx - nA;
    if (j < 9 * CIN * COUT) {
      int c = j % CIN;
      int o = (j / CIN) % COUT;
      int tap = j / (CIN * COUT);
      wBT_bf[j] = (__bf16)weight[(o * CIN + c) * 9 + tap];
    }
  }
}

// ---------------------------------------------------------------------------
// Kernel A: offset/mask conv (f32 VALU), unchanged.
// ---------------------------------------------------------------------------
__global__ __launch_bounds__(256) void offmask_kernel(
    const float* __restrict__ x, const float* __restrict__ wAT,
    const float* __restrict__ offset_b, const float* __restrict__ mask_b,
    float* __restrict__ offm) {
  int w = threadIdx.x & 127;
  int hsub = threadIdx.x >> 7;
  int bh = blockIdx.x;
  int b = bh >> 6;
  int h = ((bh & 63) << 1) + hsub;

  float acc[27];
#pragma unroll
  for (int o = 0; o < 27; ++o) acc[o] = 0.f;

  const float* xb = x + (size_t)b * CIN * HW;
  for (int c = 0; c < CIN; ++c) {
    const float* xp = xb + c * HW;
    float xv[9];
#pragma unroll
    for (int dy = 0; dy < 3; ++dy) {
      int yy = h + dy - 1;
      bool yok = (unsigned)yy < (unsigned)H;
#pragma unroll
      for (int dx = 0; dx < 3; ++dx) {
        int xx = w + dx - 1;
        bool ok = yok && ((unsigned)xx < (unsigned)W);
        xv[dy * 3 + dx] = ok ? xp[yy * W + xx] : 0.f;
      }
    }
    const float* wp = wAT + c * 9 * 28;
#pragma unroll
    for (int kk = 0; kk < 9; ++kk) {
      float v = xv[kk];
#pragma unroll
      for (int o = 0; o < 27; ++o)
        acc[o] = fmaf(v, wp[kk * 28 + o], acc[o]);
    }
  }

  size_t pix = (size_t)h * W + w;
  float* ob = offm + (size_t)b * 27 * HW;
#pragma unroll
  for (int o = 0; o < 18; ++o)
    ob[(size_t)o * HW + pix] = acc[o] + offset_b[o];
#pragma unroll
  for (int kk = 0; kk < 9; ++kk) {
    float v = acc[18 + kk] + mask_b[kk];
    ob[(size_t)(18 + kk) * HW + pix] = 1.f / (1.f + expf(-v));
  }
}

// ---------------------------------------------------------------------------
// Kernel B v4: async-DMA gather deformable conv.
// Block = 32 pixels x 4 waves (256 thr). Per tap:
//   - every lane computes its pixel's 4 corner offsets + bilinear weights
//     (mask & validity folded); lanes<32 stash weights in wt[4][32]
//   - wave cr DMA-stages raw corner cr: 48x global_load_lds, 2 ch-rows each,
//     into buf[cr][96][32] f32 (async, never sunk by compiler)
//   - __syncthreads (vmcnt drain) -> each lane combines 4 corners straight
//     into MFMA A-fragment registers (no bf16 tile round-trip)
//   - wave wv: m-tile = wv&1, n-tiles (wv>>1)*3.. ; 9 MFMAs/tap
// LDS 49.7 KB -> 3 blocks/CU; 48 indep DMA issues/wave = deep MLP.
// ---------------------------------------------------------------------------
__global__ __launch_bounds__(256, 3) void deform_kernel(
    const float* __restrict__ x, const float* __restrict__ offm,
    const __bf16* __restrict__ wBT, const float* __restrict__ bias,
    float* __restrict__ out) {
  __shared__ float buf[4][CIN][32];  // [corner][channel][pix]
  __shared__ float wt[4][32];        // [corner][pix] bilinear weights

  int t = threadIdx.x;
  int lane = t & 63;
  int wv = __builtin_amdgcn_readfirstlane(t >> 6);
  int lp = lane & 31;

  // XCD-chunked bijective swizzle (nwg=8192 % 8 == 0)
  int bid = (int)blockIdx.x;
  int nb = (bid & 7) * 1024 + (bid >> 3);
  int b = nb >> 9;
  int rem = nb & 511;
  int h = rem >> 2;
  int w0 = (rem & 3) << 5;
  int w = w0 + lp;

  f32x4 acc[3];
#pragma unroll
  for (int nt = 0; nt < 3; ++nt) acc[nt] = (f32x4){0.f, 0.f, 0.f, 0.f};

  const float* xb = x + (size_t)b * CIN * HW;
  const float* ob = offm + (size_t)b * 27 * HW;
  size_t pix = (size_t)h * W + w;

  int pixp = (wv & 1) * 16 + (lane & 15);   // A/D row this lane serves
  int cbase = (lane >> 4) * 8;              // k-chunk within 32-wide K-step
  int n0base = (wv >> 1) * 48;              // output-channel half
  const __bf16* wb = wBT + ((size_t)(n0base + (lane & 15)) * CIN + cbase);

  // prefetched offm values for the upcoming tap
  float dyv = ob[pix];
  float dxv = ob[(size_t)HW + pix];
  float mv  = ob[(size_t)18 * HW + pix];

  for (int k = 0; k < 9; ++k) {
    // ---- tap addresses & bilinear weights for pixel lp ----
    int ki = k / 3, kj = k % 3;
    float py = (float)(h - 1 + ki) + dyv;
    float px = (float)(w - 1 + kj) + dxv;
    float fy = floorf(py), fx = floorf(px);
    float wyf = py - fy, wxf = px - fx;
    int iy0 = (int)fy, ix0 = (int)fx;
    int iy1 = iy0 + 1, ix1 = ix0 + 1;
    bool y0ok = (unsigned)iy0 < (unsigned)H;
    bool y1ok = (unsigned)iy1 < (unsigned)H;
    bool x0ok = (unsigned)ix0 < (unsigned)W;
    bool x1ok = (unsigned)ix1 < (unsigned)W;
    float w00c = (y0ok && x0ok) ? (1.f - wyf) * (1.f - wxf) * mv : 0.f;
    float w01c = (y0ok && x1ok) ? (1.f - wyf) * wxf * mv : 0.f;
    float w10c = (y1ok && x0ok) ? wyf * (1.f - wxf) * mv : 0.f;
    float w11c = (y1ok && x1ok) ? wyf * wxf * mv : 0.f;
    int cy0 = min(max(iy0, 0), H - 1), cy1 = min(max(iy1, 0), H - 1);
    int cx0 = min(max(ix0, 0), W - 1), cx1 = min(max(ix1, 0), W - 1);
    int o00 = cy0 * W + cx0, o01 = cy0 * W + cx1;
    int o10 = cy1 * W + cx0, o11 = cy1 * W + cx1;

    // prefetch next tap's offm (hides under DMA drain)
    if (k < 8) {
      dyv = ob[(size_t)(2 * k + 2) * HW + pix];
      dxv = ob[(size_t)(2 * k + 3) * HW + pix];
      mv  = ob[(size_t)(19 + k) * HW + pix];
    }

    if (lane < 32) {
      wt[0][lp] = w00c; wt[1][lp] = w01c;
      wt[2][lp] = w10c; wt[3][lp] = w11c;
    }

    // ---- async corner staging: wave wv owns corner wv ----
    int ocr = (wv == 0) ? o00 : (wv == 1) ? o01 : (wv == 2) ? o10 : o11;
    const float* xcr = xb + ocr + (size_t)(lane >> 5) * HW;
#pragma unroll
    for (int i = 0; i < 48; ++i)
      GLDS(xcr + (size_t)(2 * i) * HW, &buf[wv][2 * i][0]);

    __syncthreads();  // compiler emits vmcnt(0)+lgkmcnt(0) drain -> data landed

    // ---- B-fragments (L1/L2-resident weights) ----
    const __bf16* bt = wb + (size_t)k * (COUT * CIN);
    bf16x8 bfr[3][3];
#pragma unroll
    for (int nt = 0; nt < 3; ++nt)
#pragma unroll
      for (int ks = 0; ks < 3; ++ks)
        bfr[nt][ks] = *(const bf16x8*)(bt + (size_t)nt * 16 * CIN + ks * 32);

    // ---- combine 4 corners -> A-fragments (registers) ----
    float cw0 = wt[0][pixp], cw1 = wt[1][pixp];
    float cw2 = wt[2][pixp], cw3 = wt[3][pixp];
    bf16x8 af[3];
#pragma unroll
    for (int ks = 0; ks < 3; ++ks) {
#pragma unroll
      for (int j = 0; j < 8; ++j) {
        int c = ks * 32 + cbase + j;
        float s = cw0 * buf[0][c][pixp] + cw1 * buf[1][c][pixp] +
                  cw2 * buf[2][c][pixp] + cw3 * buf[3][c][pixp];
        af[ks][j] = (__bf16)s;
      }
    }

    // ---- GEMM: 3 n-tiles x 3 K-steps ----
#pragma unroll
    for (int nt = 0; nt < 3; ++nt) {
      acc[nt] = __builtin_amdgcn_mfma_f32_16x16x32_bf16(af[0], bfr[nt][0], acc[nt], 0, 0, 0);
      acc[nt] = __builtin_amdgcn_mfma_f32_16x16x32_bf16(af[1], bfr[nt][1], acc[nt], 0, 0, 0);
      acc[nt] = __builtin_amdgcn_mfma_f32_16x16x32_bf16(af[2], bfr[nt][2], acc[nt], 0, 0, 0);
    }

    __syncthreads();  // protect buf/wt before next tap overwrites
  }

  // ---- epilogue: D col = out-channel, rows = 4 consecutive pixels ----
  float* outb = out + (size_t)b * COUT * HW + (size_t)h * W;
  int prow = w0 + (wv & 1) * 16 + ((lane >> 4) << 2);
#pragma unroll
  for (int nt = 0; nt < 3; ++nt) {
    int ch = n0base + nt * 16 + (lane & 15);
    float bv = bias[ch];
    float4 o4;
    o4.x = acc[nt][0] + bv;
    o4.y = acc[nt][1] + bv;
    o4.z = acc[nt][2] + bv;
    o4.w = acc[nt][3] + bv;
    *(float4*)(outb + (size_t)ch * HW + prow) = o4;
  }
}

// ---------------------------------------------------------------------------
extern "C" void kernel_launch(void* const* d_in, const int* in_sizes, int n_in,
                              void* d_out, int out_size, void* d_ws, size_t ws_size,
                              hipStream_t stream) {
  const float* x        = (const float*)d_in[0];
  const float* weight   = (const float*)d_in[1];
  const float* bias     = (const float*)d_in[2];
  const float* offset_w = (const float*)d_in[3];
  const float* offset_b = (const float*)d_in[4];
  const float* mask_w   = (const float*)d_in[5];
  const float* mask_b   = (const float*)d_in[6];
  float* out = (float*)d_out;

  float* offm = (float*)d_ws;                          // 16*27*16384 f32
  float* wAT  = offm + (size_t)BATCH * 27 * HW;        // 96*9*28 f32
  __bf16* wBT_bf = (__bf16*)(wAT + CIN * 9 * 28);      // 9*96*96 bf16

  const int nPrep = CIN * 9 * 28 + 9 * CIN * COUT;
  prep_weights<<<(nPrep + 255) / 256, 256, 0, stream>>>(weight, offset_w, mask_w, wAT, wBT_bf);
  offmask_kernel<<<BATCH * (H / 2), 256, 0, stream>>>(x, wAT, offset_b, mask_b, offm);
  deform_kernel<<<BATCH * H * (W / 32), 256, 0, stream>>>(x, offm, wBT_bf, bias, out);
}

// Round 6
// 649.417 us; speedup vs baseline: 1.2631x; 1.2631x over previous
//
#include <hip/hip_runtime.h>
#include <math.h>

#define W 128
#define H 128
#define HW 16384
#define CIN 96
#define COUT 96
#define BATCH 16

typedef __bf16 bf16x8 __attribute__((ext_vector_type(8)));
typedef float f32x4 __attribute__((ext_vector_type(4)));
typedef float f32x2 __attribute__((ext_vector_type(2)));
typedef unsigned int u32x4 __attribute__((ext_vector_type(4)));

// ---------------------------------------------------------------------------
// Weight prep (R2-validated layouts):
//   wAT[c][kk][28] f32: o-contiguous (o<18: offset_w, 18..26: mask_w, 27 pad)
//   wBT_bf[tap][o][c] bf16: main weight, c-contiguous per output row.
// ---------------------------------------------------------------------------
__global__ void prep_weights(const float* __restrict__ weight,
                             const float* __restrict__ offset_w,
                             const float* __restrict__ mask_w,
                             float* __restrict__ wAT,
                             __bf16* __restrict__ wBT_bf) {
  int idx = blockIdx.x * blockDim.x + threadIdx.x;
  const int nA = CIN * 9 * 28;
  if (idx < nA) {
    int o = idx % 28;
    int rest = idx / 28;
    int kk = rest % 9;
    int c = rest / 9;
    float v = 0.f;
    if (o < 18)      v = offset_w[(o * CIN + c) * 9 + kk];
    else if (o < 27) v = mask_w[((o - 18) * CIN + c) * 9 + kk];
    wAT[idx] = v;
  } else {
    int j = idx - nA;
    if (j < 9 * CIN * COUT) {
      int c = j % CIN;
      int o = (j / CIN) % COUT;
      int tap = j / (CIN * COUT);
      wBT_bf[j] = (__bf16)weight[(o * CIN + c) * 9 + tap];
    }
  }
}

// ---------------------------------------------------------------------------
// Kernel A: offset/mask conv (f32 VALU), unchanged (validated).
// ---------------------------------------------------------------------------
__global__ __launch_bounds__(256) void offmask_kernel(
    const float* __restrict__ x, const float* __restrict__ wAT,
    const float* __restrict__ offset_b, const float* __restrict__ mask_b,
    float* __restrict__ offm) {
  int w = threadIdx.x & 127;
  int hsub = threadIdx.x >> 7;
  int bh = blockIdx.x;
  int b = bh >> 6;
  int h = ((bh & 63) << 1) + hsub;

  float acc[27];
#pragma unroll
  for (int o = 0; o < 27; ++o) acc[o] = 0.f;

  const float* xb = x + (size_t)b * CIN * HW;
  for (int c = 0; c < CIN; ++c) {
    const float* xp = xb + c * HW;
    float xv[9];
#pragma unroll
    for (int dy = 0; dy < 3; ++dy) {
      int yy = h + dy - 1;
      bool yok = (unsigned)yy < (unsigned)H;
#pragma unroll
      for (int dx = 0; dx < 3; ++dx) {
        int xx = w + dx - 1;
        bool ok = yok && ((unsigned)xx < (unsigned)W);
        xv[dy * 3 + dx] = ok ? xp[yy * W + xx] : 0.f;
      }
    }
    const float* wp = wAT + c * 9 * 28;
#pragma unroll
    for (int kk = 0; kk < 9; ++kk) {
      float v = xv[kk];
#pragma unroll
      for (int o = 0; o < 27; ++o)
        acc[o] = fmaf(v, wp[kk * 28 + o], acc[o]);
    }
  }

  size_t pix = (size_t)h * W + w;
  float* ob = offm + (size_t)b * 27 * HW;
#pragma unroll
  for (int o = 0; o < 18; ++o)
    ob[(size_t)o * HW + pix] = acc[o] + offset_b[o];
#pragma unroll
  for (int kk = 0; kk < 9; ++kk) {
    float v = acc[18 + kk] + mask_b[kk];
    ob[(size_t)(18 + kk) * HW + pix] = 1.f / (1.f + expf(-v));
  }
}

// ---------------------------------------------------------------------------
// Kernel B v6: race-free register-gather deformable conv.
// Block = 64 pixels x 4 waves; waves INDEPENDENT after read-only offt prologue
// (no in-loop barriers, no shared LDS tiles -> zero cross-wave race surface).
// Per tap, per wave:
//   - 48 volatile-asm buffer_load_dwordx2 gathers (pair trick: one float2
//     covers both x-corners; clamp folded into pair weights) -> 48-deep MLP
//     the compiler cannot sink (the R3 failure mode)
//   - one s_waitcnt vmcnt(0) + sched_barrier(0)  [rule #18]
//   - combine corners -> A-frags; MFMA 6 n-tiles x 3 K-steps, B-frags from
//     global (L1-resident, R2-proven)
// ---------------------------------------------------------------------------
#define ISSUE(G, V0, V1, KS)                                                  \
  _Pragma("unroll")                                                           \
  for (int j = 0; j < 8; ++j) {                                               \
    asm volatile("buffer_load_dwordx2 %0, %1, %2, %3 offen"                   \
                 : "=v"(G[2 * j])                                             \
                 : "v"(V0), "s"(rsrc), "s"(((KS) * 32 + j) * (HW * 4)));      \
    asm volatile("buffer_load_dwordx2 %0, %1, %2, %3 offen"                   \
                 : "=v"(G[2 * j + 1])                                         \
                 : "v"(V1), "s"(rsrc), "s"(((KS) * 32 + j) * (HW * 4)));      \
  }

#define COMBINE(G, AF)                                                        \
  _Pragma("unroll")                                                           \
  for (int j = 0; j < 8; ++j) {                                               \
    float s = ay0 * G[2 * j].x + ay1 * G[2 * j].y +                           \
              by0 * G[2 * j + 1].x + by1 * G[2 * j + 1].y;                    \
    AF[j] = (__bf16)s;                                                        \
  }

__global__ __launch_bounds__(256, 2) void deform_kernel(
    const float* __restrict__ x, const float* __restrict__ offm,
    const __bf16* __restrict__ wBT, const float* __restrict__ bias,
    float* __restrict__ out) {
  __shared__ float offt[27][64];   // read-only after prologue sync

  int t = threadIdx.x;
  int lane = t & 63;
  int wv = __builtin_amdgcn_readfirstlane(t >> 6);
  int ln15 = lane & 15;

  // XCD-chunked bijective swizzle (nwg=4096 % 8 == 0)
  int bid = (int)blockIdx.x;
  int nb = (bid & 7) * 512 + (bid >> 3);
  int b = nb >> 8;
  int rem = nb & 255;
  int h = rem >> 1;
  int w0 = (rem & 1) << 6;

  int pl = (wv << 4) + ln15;      // local pixel this lane gathers/computes for
  int wg = w0 + pl;               // its global w coordinate
  int cbase = (lane >> 4) << 3;   // channel sub-chunk 0/8/16/24

  const float* xb = x + (size_t)b * CIN * HW;
  const float* ob = offm + (size_t)b * 27 * HW;

  // SRSRC for batch-b image (stride=0, bounds disabled)
  unsigned long long ba = (unsigned long long)(const void*)xb;
  u32x4 rsrc;
  rsrc.x = (unsigned)ba;
  rsrc.y = (unsigned)(ba >> 32);
  rsrc.z = 0xffffffffu;
  rsrc.w = 0x00020000u;

  // ---- prologue: offm tile -> LDS (only shared state; read-only after) ----
  for (int e = t; e < 27 * 64; e += 256) {
    int o = e >> 6, p = e & 63;
    offt[o][p] = ob[(size_t)o * HW + (size_t)h * W + w0 + p];
  }
  __syncthreads();

  f32x4 acc[6];
#pragma unroll
  for (int nt = 0; nt < 6; ++nt) acc[nt] = (f32x4){0.f, 0.f, 0.f, 0.f};

  f32x2 gA[16], gB[16], gC[16];
  const __bf16* wbase = wBT + (size_t)ln15 * CIN + cbase;

  for (int k = 0; k < 9; ++k) {
    // ---- tap geometry (LDS reads only; no vmem) ----
    float dyv = offt[2 * k][pl];
    float dxv = offt[2 * k + 1][pl];
    float mv  = offt[18 + k][pl];
    int ki = k / 3, kj = k - 3 * ki;
    float py = (float)(h - 1 + ki) + dyv;
    float px = (float)(wg - 1 + kj) + dxv;
    float fy = floorf(py), fx = floorf(px);
    float wyf = py - fy, wxf = px - fx;
    int iy0 = (int)fy, ix0 = (int)fx;
    int iy1 = iy0 + 1, ix1 = ix0 + 1;
    bool y0ok = (unsigned)iy0 < (unsigned)H;
    bool y1ok = (unsigned)iy1 < (unsigned)H;
    bool x0ok = (unsigned)ix0 < (unsigned)W;
    bool x1ok = (unsigned)ix1 < (unsigned)W;
    float w00c = (y0ok && x0ok) ? (1.f - wyf) * (1.f - wxf) * mv : 0.f;
    float w01c = (y0ok && x1ok) ? (1.f - wyf) * wxf * mv : 0.f;
    float w10c = (y1ok && x0ok) ? wyf * (1.f - wxf) * mv : 0.f;
    float w11c = (y1ok && x1ok) ? wyf * wxf * mv : 0.f;
    int cy0 = min(max(iy0, 0), H - 1), cy1 = min(max(iy1, 0), H - 1);
    int cx0 = min(max(ix0, 0), W - 1), cx1 = min(max(ix1, 0), W - 1);
    int o00 = cy0 * W + cx0, o01 = cy0 * W + cx1;
    int o10 = cy1 * W + cx0, o11 = cy1 * W + cx1;
    // pair windows [base, base+1] cover both x-corners (o01-o00 in {0,1};
    // only o00==HW-1 shifts the base, handled by the weight folding below;
    // a window straddling a row edge gets weight 0 on the stray element)
    int base0 = min(o00, HW - 2);
    int base1 = min(o10, HW - 2);
    float ay0 = (o00 == base0 ? w00c : 0.f) + (o01 == base0 ? w01c : 0.f);
    float ay1 = (w00c + w01c) - ay0;
    float by0 = (o10 == base1 ? w10c : 0.f) + (o11 == base1 ? w11c : 0.f);
    float by1 = (w10c + w11c) - by0;
    unsigned voff0 = (unsigned)((cbase * HW + base0) * 4);
    unsigned voff1 = (unsigned)((cbase * HW + base1) * 4);

    // ---- issue ALL 48 gathers (volatile asm: cannot be sunk/reordered) ----
    ISSUE(gA, voff0, voff1, 0);
    ISSUE(gB, voff0, voff1, 1);
    ISSUE(gC, voff0, voff1, 2);

    asm volatile("s_waitcnt vmcnt(0)" ::: "memory");
    __builtin_amdgcn_sched_barrier(0);   // rule #18: pin consumers below wait

    // ---- combine corners -> A-frags ----
    bf16x8 af0, af1, af2;
    COMBINE(gA, af0);
    COMBINE(gB, af1);
    COMBINE(gC, af2);

    // ---- GEMM: 6 n-tiles x 3 K-steps; B-frags from global (L1-resident) ----
    const __bf16* bt = wbase + (size_t)k * (COUT * CIN);
#pragma unroll
    for (int nt = 0; nt < 6; ++nt) {
      const __bf16* bp = bt + (size_t)nt * 16 * CIN;
      bf16x8 b0 = *(const bf16x8*)(bp);
      bf16x8 b1 = *(const bf16x8*)(bp + 32);
      bf16x8 b2 = *(const bf16x8*)(bp + 64);
      acc[nt] = __builtin_amdgcn_mfma_f32_16x16x32_bf16(af0, b0, acc[nt], 0, 0, 0);
      acc[nt] = __builtin_amdgcn_mfma_f32_16x16x32_bf16(af1, b1, acc[nt], 0, 0, 0);
      acc[nt] = __builtin_amdgcn_mfma_f32_16x16x32_bf16(af2, b2, acc[nt], 0, 0, 0);
    }
  }

  // ---- epilogue: D row = pixel, col = out channel (R2-validated layout) ----
  float* outb = out + (size_t)b * COUT * HW + (size_t)h * W;
  int prow = w0 + (wv << 4) + ((lane >> 4) << 2);
#pragma unroll
  for (int nt = 0; nt < 6; ++nt) {
    int ch = nt * 16 + ln15;
    float bv = bias[ch];
    float4 o4;
    o4.x = acc[nt][0] + bv;
    o4.y = acc[nt][1] + bv;
    o4.z = acc[nt][2] + bv;
    o4.w = acc[nt][3] + bv;
    *(float4*)(outb + (size_t)ch * HW + prow) = o4;
  }
}

// ---------------------------------------------------------------------------
extern "C" void kernel_launch(void* const* d_in, const int* in_sizes, int n_in,
                              void* d_out, int out_size, void* d_ws, size_t ws_size,
                              hipStream_t stream) {
  const float* x        = (const float*)d_in[0];
  const float* weight   = (const float*)d_in[1];
  const float* bias     = (const float*)d_in[2];
  const float* offset_w = (const float*)d_in[3];
  const float* offset_b = (const float*)d_in[4];
  const float* mask_w   = (const float*)d_in[5];
  const float* mask_b   = (const float*)d_in[6];
  float* out = (float*)d_out;

  float* offm = (float*)d_ws;                          // 16*27*16384 f32
  float* wAT  = offm + (size_t)BATCH * 27 * HW;        // 96*9*28 f32
  __bf16* wBT_bf = (__bf16*)(wAT + CIN * 9 * 28);      // 9*96*96 bf16

  const int nPrep = CIN * 9 * 28 + 9 * CIN * COUT;
  prep_weights<<<(nPrep + 255) / 256, 256, 0, stream>>>(weight, offset_w, mask_w, wAT, wBT_bf);
  offmask_kernel<<<BATCH * (H / 2), 256, 0, stream>>>(x, wAT, offset_b, mask_b, offm);
  deform_kernel<<<BATCH * H * (W / 64), 256, 0, stream>>>(x, offm, wBT_bf, bias, out);
}

// Round 8
// 477.151 us; speedup vs baseline: 1.7192x; 1.3610x over previous
//
#include <hip/hip_runtime.h>
#include <math.h>

#define W 128
#define H 128
#define HW 16384
#define CIN 96
#define COUT 96
#define BATCH 16
#define NPIX (BATCH * HW)

typedef __bf16 bf16x8 __attribute__((ext_vector_type(8)));
typedef float f32x4 __attribute__((ext_vector_type(4)));
typedef unsigned int u32x4 __attribute__((ext_vector_type(4)));

__device__ inline float bflo(unsigned d) { union { unsigned u; float f; } t; t.u = d << 16; return t.f; }
__device__ inline float bfhi(unsigned d) { union { unsigned u; float f; } t; t.u = d & 0xffff0000u; return t.f; }

// ---------------------------------------------------------------------------
// Weight prep (R2/R6-validated layouts):
//   wAT[c][kk][28] f32: o-contiguous (o<18: offset_w, 18..26: mask_w, 27 pad)
//   wBT_bf[tap][o][c] bf16: main weight, c-contiguous per output row.
// ---------------------------------------------------------------------------
__global__ void prep_weights(const float* __restrict__ weight,
                             const float* __restrict__ offset_w,
                             const float* __restrict__ mask_w,
                             float* __restrict__ wAT,
                             __bf16* __restrict__ wBT_bf) {
  int idx = blockIdx.x * blockDim.x + threadIdx.x;
  const int nA = CIN * 9 * 28;
  if (idx < nA) {
    int o = idx % 28;
    int rest = idx / 28;
    int kk = rest % 9;
    int c = rest / 9;
    float v = 0.f;
    if (o < 18)      v = offset_w[(o * CIN + c) * 9 + kk];
    else if (o < 27) v = mask_w[((o - 18) * CIN + c) * 9 + kk];
    wAT[idx] = v;
  } else {
    int j = idx - nA;
    if (j < 9 * CIN * COUT) {
      int c = j % CIN;
      int o = (j / CIN) % COUT;
      int tap = j / (CIN * COUT);
      wBT_bf[j] = (__bf16)weight[(o * CIN + c) * 9 + tap];
    }
  }
}

// ---------------------------------------------------------------------------
// NHWC relayout: x[b][c][h][w] f32 -> xT[b][h][w][c] bf16.
// ---------------------------------------------------------------------------
__global__ __launch_bounds__(256) void nhwc_kernel(const float* __restrict__ x,
                                                   __bf16* __restrict__ xT) {
  int tid = blockIdx.x * 256 + threadIdx.x;
  int b = tid >> 14, pix = tid & (HW - 1);
  const float* xp = x + (size_t)b * CIN * HW + pix;
  __bf16* op = xT + (size_t)tid * CIN;
#pragma unroll
  for (int c0 = 0; c0 < CIN; c0 += 8) {
    bf16x8 v;
#pragma unroll
    for (int j = 0; j < 8; ++j) v[j] = (__bf16)xp[(size_t)(c0 + j) * HW];
    *(bf16x8*)(op + c0) = v;
  }
}

// ---------------------------------------------------------------------------
// Kernel A: offset/mask conv (f32 VALU), unchanged (validated).
// ---------------------------------------------------------------------------
__global__ __launch_bounds__(256) void offmask_kernel(
    const float* __restrict__ x, const float* __restrict__ wAT,
    const float* __restrict__ offset_b, const float* __restrict__ mask_b,
    float* __restrict__ offm) {
  int w = threadIdx.x & 127;
  int hsub = threadIdx.x >> 7;
  int bh = blockIdx.x;
  int b = bh >> 6;
  int h = ((bh & 63) << 1) + hsub;

  float acc[27];
#pragma unroll
  for (int o = 0; o < 27; ++o) acc[o] = 0.f;

  const float* xb = x + (size_t)b * CIN * HW;
  for (int c = 0; c < CIN; ++c) {
    const float* xp = xb + c * HW;
    float xv[9];
#pragma unroll
    for (int dy = 0; dy < 3; ++dy) {
      int yy = h + dy - 1;
      bool yok = (unsigned)yy < (unsigned)H;
#pragma unroll
      for (int dx = 0; dx < 3; ++dx) {
        int xx = w + dx - 1;
        bool ok = yok && ((unsigned)xx < (unsigned)W);
        xv[dy * 3 + dx] = ok ? xp[yy * W + xx] : 0.f;
      }
    }
    const float* wp = wAT + c * 9 * 28;
#pragma unroll
    for (int kk = 0; kk < 9; ++kk) {
      float v = xv[kk];
#pragma unroll
      for (int o = 0; o < 27; ++o)
        acc[o] = fmaf(v, wp[kk * 28 + o], acc[o]);
    }
  }

  size_t pix = (size_t)h * W + w;
  float* ob = offm + (size_t)b * 27 * HW;
#pragma unroll
  for (int o = 0; o < 18; ++o)
    ob[(size_t)o * HW + pix] = acc[o] + offset_b[o];
#pragma unroll
  for (int kk = 0; kk < 9; ++kk) {
    float v = acc[18 + kk] + mask_b[kk];
    ob[(size_t)(18 + kk) * HW + pix] = 1.f / (1.f + expf(-v));
  }
}

// ---------------------------------------------------------------------------
// Kernel B v8: NHWC register-gather deformable conv, R6 sync skeleton.
// Block = 64 pixels x 4 waves; waves independent after read-only offt
// prologue (no in-loop barriers). Per tap per wave:
//   - 12 volatile-asm buffer_load_dwordx4 gathers (4 corners x 3 K-steps;
//     16B/lane of contiguous NHWC channels) -> single 48-VGPR landing zone
//   - one s_waitcnt vmcnt(0) + sched_barrier(0)   [rule #18]
//   - combine corners (validity/mask folded into 4 f32 weights) -> A-frags
//   - B-frags via plain C++ loads (compiler waitcnts can only over-wait
//     given our per-tap drain); MFMA 6 n-tiles x 3 K-steps.
// ---------------------------------------------------------------------------
#define GISS(K, G, WD) {                                                      \
    float dyv = offt[2 * (K)][pl];                                            \
    float dxv = offt[2 * (K) + 1][pl];                                        \
    float mv  = offt[18 + (K)][pl];                                           \
    int ki = (K) / 3, kj = (K) % 3;                                           \
    float py = (float)(h - 1 + ki) + dyv;                                     \
    float px = (float)(wg - 1 + kj) + dxv;                                    \
    float fy = floorf(py), fx = floorf(px);                                   \
    float wyf = py - fy, wxf = px - fx;                                       \
    int iy0 = (int)fy, ix0 = (int)fx;                                         \
    int iy1 = iy0 + 1, ix1 = ix0 + 1;                                         \
    bool y0ok = (unsigned)iy0 < (unsigned)H;                                  \
    bool y1ok = (unsigned)iy1 < (unsigned)H;                                  \
    bool x0ok = (unsigned)ix0 < (unsigned)W;                                  \
    bool x1ok = (unsigned)ix1 < (unsigned)W;                                  \
    WD[0] = (y0ok && x0ok) ? (1.f - wyf) * (1.f - wxf) * mv : 0.f;            \
    WD[1] = (y0ok && x1ok) ? (1.f - wyf) * wxf * mv : 0.f;                    \
    WD[2] = (y1ok && x0ok) ? wyf * (1.f - wxf) * mv : 0.f;                    \
    WD[3] = (y1ok && x1ok) ? wyf * wxf * mv : 0.f;                            \
    int cy0 = min(max(iy0, 0), H - 1), cy1 = min(max(iy1, 0), H - 1);         \
    int cx0 = min(max(ix0, 0), W - 1), cx1 = min(max(ix1, 0), W - 1);         \
    unsigned v00 = (unsigned)((cy0 * W + cx0) * 192) + choff;                 \
    unsigned v01 = (unsigned)((cy0 * W + cx1) * 192) + choff;                 \
    unsigned v10 = (unsigned)((cy1 * W + cx0) * 192) + choff;                 \
    unsigned v11 = (unsigned)((cy1 * W + cx1) * 192) + choff;                 \
    _Pragma("unroll") for (int ks = 0; ks < 3; ++ks) {                        \
      asm volatile("buffer_load_dwordx4 %0, %1, %2, %3 offen"                 \
                   : "=v"(G[ks * 4 + 0]) : "v"(v00), "s"(rsrcX), "s"(ks * 64)); \
      asm volatile("buffer_load_dwordx4 %0, %1, %2, %3 offen"                 \
                   : "=v"(G[ks * 4 + 1]) : "v"(v01), "s"(rsrcX), "s"(ks * 64)); \
      asm volatile("buffer_load_dwordx4 %0, %1, %2, %3 offen"                 \
                   : "=v"(G[ks * 4 + 2]) : "v"(v10), "s"(rsrcX), "s"(ks * 64)); \
      asm volatile("buffer_load_dwordx4 %0, %1, %2, %3 offen"                 \
                   : "=v"(G[ks * 4 + 3]) : "v"(v11), "s"(rsrcX), "s"(ks * 64)); \
    } }

#define COMBINE_KS(G, KS, WV, AF)                                             \
  _Pragma("unroll") for (int j = 0; j < 8; ++j) {                             \
    unsigned d00 = G[(KS) * 4 + 0][j >> 1], d01 = G[(KS) * 4 + 1][j >> 1];    \
    unsigned d10 = G[(KS) * 4 + 2][j >> 1], d11 = G[(KS) * 4 + 3][j >> 1];    \
    float v00 = (j & 1) ? bfhi(d00) : bflo(d00);                              \
    float v01 = (j & 1) ? bfhi(d01) : bflo(d01);                              \
    float v10 = (j & 1) ? bfhi(d10) : bflo(d10);                              \
    float v11 = (j & 1) ? bfhi(d11) : bflo(d11);                              \
    AF[j] = (__bf16)(WV[0] * v00 + WV[1] * v01 + WV[2] * v10 + WV[3] * v11);  \
  }

__global__ __launch_bounds__(256, 2) void deform_kernel(
    const __bf16* __restrict__ xT, const float* __restrict__ offm,
    const __bf16* __restrict__ wBT, const float* __restrict__ bias,
    float* __restrict__ out) {
  __shared__ float offt[27][64];   // read-only after prologue sync

  int t = threadIdx.x;
  int lane = t & 63;
  int wv = __builtin_amdgcn_readfirstlane(t >> 6);
  int ln15 = lane & 15;

  // XCD-chunked bijective swizzle (nwg=4096 % 8 == 0)
  int bid = (int)blockIdx.x;
  int nb = (bid & 7) * 512 + (bid >> 3);
  int b = nb >> 8;
  int rem = nb & 255;
  int h = rem >> 1;
  int w0 = (rem & 1) << 6;

  int pl = (wv << 4) + ln15;            // local pixel this lane computes
  int wg = w0 + pl;                     // its global w coordinate
  unsigned choff = (unsigned)((lane >> 4) << 4);  // channel-chunk byte offset

  const __bf16* xb = xT + (size_t)b * HW * CIN;
  const float* ob = offm + (size_t)b * 27 * HW;

  // SRSRC for batch-b NHWC image (stride=0, bounds disabled)
  unsigned long long ba = (unsigned long long)(const void*)xb;
  u32x4 rsrcX;
  rsrcX.x = (unsigned)ba; rsrcX.y = (unsigned)(ba >> 32);
  rsrcX.z = 0xffffffffu;  rsrcX.w = 0x00020000u;

  // ---- prologue: offm tile -> LDS (only shared state; read-only after) ----
  for (int e = t; e < 27 * 64; e += 256) {
    int o = e >> 6, p = e & 63;
    offt[o][p] = ob[(size_t)o * HW + (size_t)h * W + w0 + p];
  }
  __syncthreads();

  f32x4 acc[6];
#pragma unroll
  for (int nt = 0; nt < 6; ++nt) acc[nt] = (f32x4){0.f, 0.f, 0.f, 0.f};

  u32x4 g[12];
  f32x4 wd;
  const __bf16* wbase = wBT + (size_t)ln15 * CIN + ((lane >> 4) << 3);

  for (int k = 0; k < 9; ++k) {
    // ---- issue ALL 12 gathers (volatile asm: cannot be sunk/reordered) ----
    GISS(k, g, wd);

    asm volatile("s_waitcnt vmcnt(0)" ::: "memory");
    __builtin_amdgcn_sched_barrier(0);   // rule #18: pin consumers below wait

    // ---- combine corners -> A-frags ----
    bf16x8 af0, af1, af2;
    COMBINE_KS(g, 0, wd, af0);
    COMBINE_KS(g, 1, wd, af1);
    COMBINE_KS(g, 2, wd, af2);

    // ---- GEMM: 6 n-tiles x 3 K-steps; B-frags from global (L1-resident) ----
    const __bf16* bt = wbase + (size_t)k * (COUT * CIN);
#pragma unroll
    for (int nt = 0; nt < 6; ++nt) {
      const __bf16* bp = bt + (size_t)nt * 16 * CIN;
      bf16x8 b0 = *(const bf16x8*)(bp);
      bf16x8 b1 = *(const bf16x8*)(bp + 32);
      bf16x8 b2 = *(const bf16x8*)(bp + 64);
      acc[nt] = __builtin_amdgcn_mfma_f32_16x16x32_bf16(af0, b0, acc[nt], 0, 0, 0);
      acc[nt] = __builtin_amdgcn_mfma_f32_16x16x32_bf16(af1, b1, acc[nt], 0, 0, 0);
      acc[nt] = __builtin_amdgcn_mfma_f32_16x16x32_bf16(af2, b2, acc[nt], 0, 0, 0);
    }
  }

  // ---- epilogue: D row = pixel, col = out channel (validated layout) ----
  float* outb = out + (size_t)b * COUT * HW + (size_t)h * W;
  int prow = w0 + (wv << 4) + ((lane >> 4) << 2);
#pragma unroll
  for (int nt = 0; nt < 6; ++nt) {
    int ch = nt * 16 + ln15;
    float bv = bias[ch];
    float4 o4;
    o4.x = acc[nt][0] + bv;
    o4.y = acc[nt][1] + bv;
    o4.z = acc[nt][2] + bv;
    o4.w = acc[nt][3] + bv;
    *(float4*)(outb + (size_t)ch * HW + prow) = o4;
  }
}

// ---------------------------------------------------------------------------
extern "C" void kernel_launch(void* const* d_in, const int* in_sizes, int n_in,
                              void* d_out, int out_size, void* d_ws, size_t ws_size,
                              hipStream_t stream) {
  const float* x        = (const float*)d_in[0];
  const float* weight   = (const float*)d_in[1];
  const float* bias     = (const float*)d_in[2];
  const float* offset_w = (const float*)d_in[3];
  const float* offset_b = (const float*)d_in[4];
  const float* mask_w   = (const float*)d_in[5];
  const float* mask_b   = (const float*)d_in[6];
  float* out = (float*)d_out;

  __bf16* xT  = (__bf16*)d_ws;                               // NPIX*96 bf16 (50.3 MB)
  float* offm = (float*)(xT + (size_t)NPIX * CIN);           // 16*27*16384 f32 (28.3 MB)
  float* wAT  = offm + (size_t)BATCH * 27 * HW;              // 96*9*28 f32
  __bf16* wBT_bf = (__bf16*)(wAT + CIN * 9 * 28);            // 9*96*96 bf16

  const int nPrep = CIN * 9 * 28 + 9 * CIN * COUT;
  prep_weights<<<(nPrep + 255) / 256, 256, 0, stream>>>(weight, offset_w, mask_w, wAT, wBT_bf);
  nhwc_kernel<<<NPIX / 256, 256, 0, stream>>>(x, xT);
  offmask_kernel<<<BATCH * (H / 2), 256, 0, stream>>>(x, wAT, offset_b, mask_b, offm);
  deform_kernel<<<BATCH * H * (W / 64), 256, 0, stream>>>(xT, offm, wBT_bf, bias, out);
}

// Round 9
// 363.244 us; speedup vs baseline: 2.2583x; 1.3136x over previous
//
#include <hip/hip_runtime.h>
#include <math.h>

#define W 128
#define H 128
#define HW 16384
#define CIN 96
#define COUT 96
#define BATCH 16
#define NPIX (BATCH * HW)
#define BPITCH 104                 // padded B row pitch (bf16): 52 dwords -> <=2-way banks
#define BTAP (COUT * BPITCH)       // 9984 elems per tap image
#define BSTG 10240                 // LDS B buffer elems (20480 B, covers DMA overshoot)

typedef __bf16 bf16x8 __attribute__((ext_vector_type(8)));
typedef float f32x4 __attribute__((ext_vector_type(4)));
typedef unsigned int u32x4 __attribute__((ext_vector_type(4)));

typedef const unsigned int __attribute__((address_space(1))) gu32;
typedef unsigned int __attribute__((address_space(3))) lu32;
#define GLDS16(g, l) __builtin_amdgcn_global_load_lds((gu32*)(g), (lu32*)(l), 16, 0, 0)

__device__ inline float bflo(unsigned d) { union { unsigned u; float f; } t; t.u = d << 16; return t.f; }
__device__ inline float bfhi(unsigned d) { union { unsigned u; float f; } t; t.u = d & 0xffff0000u; return t.f; }

// ---------------------------------------------------------------------------
// Weight prep:
//   wAT[c][kk][28] f32 (validated)
//   wBTp[tap][o][104] bf16: padded LDS image of the main weights (zero pad),
//     DMA'd linearly per tap.
// ---------------------------------------------------------------------------
__global__ void prep_weights(const float* __restrict__ weight,
                             const float* __restrict__ offset_w,
                             const float* __restrict__ mask_w,
                             float* __restrict__ wAT,
                             __bf16* __restrict__ wBTp) {
  int idx = blockIdx.x * blockDim.x + threadIdx.x;
  const int nA = CIN * 9 * 28;
  if (idx < nA) {
    int o = idx % 28;
    int rest = idx / 28;
    int kk = rest % 9;
    int c = rest / 9;
    float v = 0.f;
    if (o < 18)      v = offset_w[(o * CIN + c) * 9 + kk];
    else if (o < 27) v = mask_w[((o - 18) * CIN + c) * 9 + kk];
    wAT[idx] = v;
  } else {
    int j = idx - nA;
    if (j < 9 * BTAP + 256) {   // +256: zero the DMA-overshoot slack too
      int c = j % BPITCH;
      int o = (j / BPITCH) % COUT;
      int tap = j / BTAP;
      float v = 0.f;
      if (tap < 9 && c < CIN) v = weight[(o * CIN + c) * 9 + tap];
      wBTp[j] = (__bf16)v;
    }
  }
}

// ---------------------------------------------------------------------------
// NHWC relayout: x[b][c][h][w] f32 -> xT[b][h][w][c] bf16 (validated).
// ---------------------------------------------------------------------------
__global__ __launch_bounds__(256) void nhwc_kernel(const float* __restrict__ x,
                                                   __bf16* __restrict__ xT) {
  int tid = blockIdx.x * 256 + threadIdx.x;
  int b = tid >> 14, pix = tid & (HW - 1);
  const float* xp = x + (size_t)b * CIN * HW + pix;
  __bf16* op = xT + (size_t)tid * CIN;
#pragma unroll
  for (int c0 = 0; c0 < CIN; c0 += 8) {
    bf16x8 v;
#pragma unroll
    for (int j = 0; j < 8; ++j) v[j] = (__bf16)xp[(size_t)(c0 + j) * HW];
    *(bf16x8*)(op + c0) = v;
  }
}

// ---------------------------------------------------------------------------
// Kernel A: offset/mask conv (f32 VALU), unchanged (validated).
// ---------------------------------------------------------------------------
__global__ __launch_bounds__(256) void offmask_kernel(
    const float* __restrict__ x, const float* __restrict__ wAT,
    const float* __restrict__ offset_b, const float* __restrict__ mask_b,
    float* __restrict__ offm) {
  int w = threadIdx.x & 127;
  int hsub = threadIdx.x >> 7;
  int bh = blockIdx.x;
  int b = bh >> 6;
  int h = ((bh & 63) << 1) + hsub;

  float acc[27];
#pragma unroll
  for (int o = 0; o < 27; ++o) acc[o] = 0.f;

  const float* xb = x + (size_t)b * CIN * HW;
  for (int c = 0; c < CIN; ++c) {
    const float* xp = xb + c * HW;
    float xv[9];
#pragma unroll
    for (int dy = 0; dy < 3; ++dy) {
      int yy = h + dy - 1;
      bool yok = (unsigned)yy < (unsigned)H;
#pragma unroll
      for (int dx = 0; dx < 3; ++dx) {
        int xx = w + dx - 1;
        bool ok = yok && ((unsigned)xx < (unsigned)W);
        xv[dy * 3 + dx] = ok ? xp[yy * W + xx] : 0.f;
      }
    }
    const float* wp = wAT + c * 9 * 28;
#pragma unroll
    for (int kk = 0; kk < 9; ++kk) {
      float v = xv[kk];
#pragma unroll
      for (int o = 0; o < 27; ++o)
        acc[o] = fmaf(v, wp[kk * 28 + o], acc[o]);
    }
  }

  size_t pix = (size_t)h * W + w;
  float* ob = offm + (size_t)b * 27 * HW;
#pragma unroll
  for (int o = 0; o < 18; ++o)
    ob[(size_t)o * HW + pix] = acc[o] + offset_b[o];
#pragma unroll
  for (int kk = 0; kk < 9; ++kk) {
    float v = acc[18 + kk] + mask_b[kk];
    ob[(size_t)(18 + kk) * HW + pix] = 1.f / (1.f + expf(-v));
  }
}

// ---------------------------------------------------------------------------
// Kernel B v9: R8 + B-weights staged per-tap into LDS (single-buffered,
// __syncthreads-protected -> zero new race surface).
// Per tap:
//   - 5 global_load_lds per wave stage the 19.9KB padded B-tap image (async,
//     vmcnt-counted, no VGPR round-trip, no compiler waits)
//   - 12 volatile-asm dwordx4 gathers (R8-proven)
//   - asm vmcnt(0) + sched_barrier  -> own gathers + own B-DMA done
//   - combine corners -> A-frags    (hides before the barrier)
//   - __syncthreads                 -> ALL waves' B-DMA landed
//   - ds_read B-frags (lgkm pipe, 2-way banks = free) + 18 MFMA
//   - __syncthreads                 -> buffer free for next tap's DMA
// Moves 18 scattered B-loads/wave-tap (~60% of TA line traffic) off the
// vmem pipe onto the idle LDS pipe.
// ---------------------------------------------------------------------------
#define GISS(K, G, WD) {                                                      \
    float dyv = offt[2 * (K)][pl];                                            \
    float dxv = offt[2 * (K) + 1][pl];                                        \
    float mv  = offt[18 + (K)][pl];                                           \
    int ki = (K) / 3, kj = (K) % 3;                                           \
    float py = (float)(h - 1 + ki) + dyv;                                     \
    float px = (float)(wg - 1 + kj) + dxv;                                    \
    float fy = floorf(py), fx = floorf(px);                                   \
    float wyf = py - fy, wxf = px - fx;                                       \
    int iy0 = (int)fy, ix0 = (int)fx;                                         \
    int iy1 = iy0 + 1, ix1 = ix0 + 1;                                         \
    bool y0ok = (unsigned)iy0 < (unsigned)H;                                  \
    bool y1ok = (unsigned)iy1 < (unsigned)H;                                  \
    bool x0ok = (unsigned)ix0 < (unsigned)W;                                  \
    bool x1ok = (unsigned)ix1 < (unsigned)W;                                  \
    WD[0] = (y0ok && x0ok) ? (1.f - wyf) * (1.f - wxf) * mv : 0.f;            \
    WD[1] = (y0ok && x1ok) ? (1.f - wyf) * wxf * mv : 0.f;                    \
    WD[2] = (y1ok && x0ok) ? wyf * (1.f - wxf) * mv : 0.f;                    \
    WD[3] = (y1ok && x1ok) ? wyf * wxf * mv : 0.f;                            \
    int cy0 = min(max(iy0, 0), H - 1), cy1 = min(max(iy1, 0), H - 1);         \
    int cx0 = min(max(ix0, 0), W - 1), cx1 = min(max(ix1, 0), W - 1);         \
    unsigned v00 = (unsigned)((cy0 * W + cx0) * 192) + choff;                 \
    unsigned v01 = (unsigned)((cy0 * W + cx1) * 192) + choff;                 \
    unsigned v10 = (unsigned)((cy1 * W + cx0) * 192) + choff;                 \
    unsigned v11 = (unsigned)((cy1 * W + cx1) * 192) + choff;                 \
    _Pragma("unroll") for (int ks = 0; ks < 3; ++ks) {                        \
      asm volatile("buffer_load_dwordx4 %0, %1, %2, %3 offen"                 \
                   : "=v"(G[ks * 4 + 0]) : "v"(v00), "s"(rsrcX), "s"(ks * 64)); \
      asm volatile("buffer_load_dwordx4 %0, %1, %2, %3 offen"                 \
                   : "=v"(G[ks * 4 + 1]) : "v"(v01), "s"(rsrcX), "s"(ks * 64)); \
      asm volatile("buffer_load_dwordx4 %0, %1, %2, %3 offen"                 \
                   : "=v"(G[ks * 4 + 2]) : "v"(v10), "s"(rsrcX), "s"(ks * 64)); \
      asm volatile("buffer_load_dwordx4 %0, %1, %2, %3 offen"                 \
                   : "=v"(G[ks * 4 + 3]) : "v"(v11), "s"(rsrcX), "s"(ks * 64)); \
    } }

#define COMBINE_KS(G, KS, WV, AF)                                             \
  _Pragma("unroll") for (int j = 0; j < 8; ++j) {                             \
    unsigned d00 = G[(KS) * 4 + 0][j >> 1], d01 = G[(KS) * 4 + 1][j >> 1];    \
    unsigned d10 = G[(KS) * 4 + 2][j >> 1], d11 = G[(KS) * 4 + 3][j >> 1];    \
    float v00 = (j & 1) ? bfhi(d00) : bflo(d00);                              \
    float v01 = (j & 1) ? bfhi(d01) : bflo(d01);                              \
    float v10 = (j & 1) ? bfhi(d10) : bflo(d10);                              \
    float v11 = (j & 1) ? bfhi(d11) : bflo(d11);                              \
    AF[j] = (__bf16)(WV[0] * v00 + WV[1] * v01 + WV[2] * v10 + WV[3] * v11);  \
  }

__global__ __launch_bounds__(256, 3) void deform_kernel(
    const __bf16* __restrict__ xT, const float* __restrict__ offm,
    const __bf16* __restrict__ wBTp, const float* __restrict__ bias,
    float* __restrict__ out) {
  __shared__ alignas(16) __bf16 Blds[BSTG];   // single-buffered B-tap image
  __shared__ float offt[27][64];              // read-only after prologue

  int t = threadIdx.x;
  int lane = t & 63;
  int wv = __builtin_amdgcn_readfirstlane(t >> 6);
  int ln15 = lane & 15;

  // XCD-chunked bijective swizzle (nwg=4096 % 8 == 0)
  int bid = (int)blockIdx.x;
  int nb = (bid & 7) * 512 + (bid >> 3);
  int b = nb >> 8;
  int rem = nb & 255;
  int h = rem >> 1;
  int w0 = (rem & 1) << 6;

  int pl = (wv << 4) + ln15;            // local pixel this lane computes
  int wg = w0 + pl;                     // its global w coordinate
  unsigned choff = (unsigned)((lane >> 4) << 4);  // channel-chunk byte offset

  const __bf16* xb = xT + (size_t)b * HW * CIN;
  const float* ob = offm + (size_t)b * 27 * HW;

  // SRSRC for batch-b NHWC image (stride=0, bounds disabled)
  unsigned long long ba = (unsigned long long)(const void*)xb;
  u32x4 rsrcX;
  rsrcX.x = (unsigned)ba; rsrcX.y = (unsigned)(ba >> 32);
  rsrcX.z = 0xffffffffu;  rsrcX.w = 0x00020000u;

  // ---- prologue: offm tile -> LDS ----
  for (int e = t; e < 27 * 64; e += 256) {
    int o = e >> 6, p = e & 63;
    offt[o][p] = ob[(size_t)o * HW + (size_t)h * W + w0 + p];
  }
  __syncthreads();

  f32x4 acc[6];
#pragma unroll
  for (int nt = 0; nt < 6; ++nt) acc[nt] = (f32x4){0.f, 0.f, 0.f, 0.f};

  u32x4 g[12];
  f32x4 wd;
  // per-lane LDS base for B-fragments: row = nt*16+ln15 (pitch 104), chunk
  const __bf16* bfrag = Blds + (size_t)ln15 * BPITCH + ((lane >> 4) << 3);

  for (int k = 0; k < 9; ++k) {
    // ---- stage tap-k B image into LDS (async, 5 instrs/wave) ----
    {
      const __bf16* src = wBTp + (size_t)k * BTAP + (size_t)wv * 2560 + (size_t)lane * 8;
      __bf16* dst = Blds + wv * 2560;
#pragma unroll
      for (int q = 0; q < 5; ++q)
        GLDS16(src + q * 512, dst + q * 512);
    }

    // ---- issue 12 gathers (volatile asm) ----
    GISS(k, g, wd);

    asm volatile("s_waitcnt vmcnt(0)" ::: "memory");  // own gathers + own DMA
    __builtin_amdgcn_sched_barrier(0);                // rule #18

    // ---- combine corners -> A-frags (hides before the barrier) ----
    bf16x8 af0, af1, af2;
    COMBINE_KS(g, 0, wd, af0);
    COMBINE_KS(g, 1, wd, af1);
    COMBINE_KS(g, 2, wd, af2);

    __syncthreads();   // all waves' B-DMA landed -> Blds valid

    // ---- GEMM: 6 n-tiles x 3 K-steps; B-frags from LDS (lgkm pipe) ----
#pragma unroll
    for (int nt = 0; nt < 6; ++nt) {
      const __bf16* bp = bfrag + nt * 16 * BPITCH;
      bf16x8 b0 = *(const bf16x8*)(bp);
      bf16x8 b1 = *(const bf16x8*)(bp + 32);
      bf16x8 b2 = *(const bf16x8*)(bp + 64);
      acc[nt] = __builtin_amdgcn_mfma_f32_16x16x32_bf16(af0, b0, acc[nt], 0, 0, 0);
      acc[nt] = __builtin_amdgcn_mfma_f32_16x16x32_bf16(af1, b1, acc[nt], 0, 0, 0);
      acc[nt] = __builtin_amdgcn_mfma_f32_16x16x32_bf16(af2, b2, acc[nt], 0, 0, 0);
    }

    __syncthreads();   // all waves done reading -> buffer free for next DMA
  }

  // ---- epilogue: D row = pixel, col = out channel (validated layout) ----
  float* outb = out + (size_t)b * COUT * HW + (size_t)h * W;
  int prow = w0 + (wv << 4) + ((lane >> 4) << 2);
#pragma unroll
  for (int nt = 0; nt < 6; ++nt) {
    int ch = nt * 16 + ln15;
    float bv = bias[ch];
    float4 o4;
    o4.x = acc[nt][0] + bv;
    o4.y = acc[nt][1] + bv;
    o4.z = acc[nt][2] + bv;
    o4.w = acc[nt][3] + bv;
    *(float4*)(outb + (size_t)ch * HW + prow) = o4;
  }
}

// ---------------------------------------------------------------------------
extern "C" void kernel_launch(void* const* d_in, const int* in_sizes, int n_in,
                              void* d_out, int out_size, void* d_ws, size_t ws_size,
                              hipStream_t stream) {
  const float* x        = (const float*)d_in[0];
  const float* weight   = (const float*)d_in[1];
  const float* bias     = (const float*)d_in[2];
  const float* offset_w = (const float*)d_in[3];
  const float* offset_b = (const float*)d_in[4];
  const float* mask_w   = (const float*)d_in[5];
  const float* mask_b   = (const float*)d_in[6];
  float* out = (float*)d_out;

  __bf16* xT  = (__bf16*)d_ws;                               // NPIX*96 bf16
  float* offm = (float*)(xT + (size_t)NPIX * CIN);           // 16*27*16384 f32
  float* wAT  = offm + (size_t)BATCH * 27 * HW;              // 96*9*28 f32
  __bf16* wBTp = (__bf16*)(wAT + CIN * 9 * 28);              // 9*9984 + 256 slack bf16

  const int nPrep = CIN * 9 * 28 + 9 * BTAP + 256;
  prep_weights<<<(nPrep + 255) / 256, 256, 0, stream>>>(weight, offset_w, mask_w, wAT, wBTp);
  nhwc_kernel<<<NPIX / 256, 256, 0, stream>>>(x, xT);
  offmask_kernel<<<BATCH * (H / 2), 256, 0, stream>>>(x, wAT, offset_b, mask_b, offm);
  deform_kernel<<<BATCH * H * (W / 64), 256, 0, stream>>>(xT, offm, wBTp, bias, out);
}

// Round 10
// 285.378 us; speedup vs baseline: 2.8744x; 1.2729x over previous
//
#include <hip/hip_runtime.h>
#include <math.h>

#define W 128
#define H 128
#define HW 16384
#define CIN 96
#define COUT 96
#define BATCH 16
#define NPIX (BATCH * HW)
#define BPITCH 104                 // padded B row pitch (bf16): 52 dwords -> <=2-way banks
#define BTAP (COUT * BPITCH)       // 9984 elems per tap image
#define BSTG 10240                 // LDS B buffer elems (20480 B, covers DMA overshoot)
#define NOT (27 * 32 * 32)         // wOT elems: 27 K-steps x 32 out x 32 k

typedef __bf16 bf16x8 __attribute__((ext_vector_type(8)));
typedef float f32x4 __attribute__((ext_vector_type(4)));
typedef unsigned int u32x4 __attribute__((ext_vector_type(4)));

typedef const unsigned int __attribute__((address_space(1))) gu32;
typedef unsigned int __attribute__((address_space(3))) lu32;
#define GLDS16(g, l) __builtin_amdgcn_global_load_lds((gu32*)(g), (lu32*)(l), 16, 0, 0)

__device__ inline float bflo(unsigned d) { union { unsigned u; float f; } t; t.u = d << 16; return t.f; }
__device__ inline float bfhi(unsigned d) { union { unsigned u; float f; } t; t.u = d & 0xffff0000u; return t.f; }

// ---------------------------------------------------------------------------
// Weight prep:
//   wOT[ks][o(32,pad)][c(32)] bf16: offset/mask weights as MFMA B-tiles
//     (ks = tap*3 + s; channel group cg = (ks%3)*32 + c; o>=27 -> 0)
//   wBTp[tap][o][104] bf16: padded deform weights for LDS DMA (validated).
// ---------------------------------------------------------------------------
__global__ void prep_weights(const float* __restrict__ weight,
                             const float* __restrict__ offset_w,
                             const float* __restrict__ mask_w,
                             __bf16* __restrict__ wOT,
                             __bf16* __restrict__ wBTp) {
  int idx = blockIdx.x * blockDim.x + threadIdx.x;
  if (idx < NOT) {
    int c = idx & 31;
    int o = (idx >> 5) & 31;
    int ks = idx >> 10;
    int tap = ks / 3;
    int cg = (ks % 3) * 32 + c;
    float v = 0.f;
    if (o < 18)      v = offset_w[(o * CIN + cg) * 9 + tap];
    else if (o < 27) v = mask_w[((o - 18) * CIN + cg) * 9 + tap];
    wOT[idx] = (__bf16)v;
  } else {
    int j = idx - NOT;
    if (j < 9 * BTAP + 256) {   // +256: zero the DMA-overshoot slack too
      int c = j % BPITCH;
      int o = (j / BPITCH) % COUT;
      int tap = j / BTAP;
      float v = 0.f;
      if (tap < 9 && c < CIN) v = weight[(o * CIN + c) * 9 + tap];
      wBTp[j] = (__bf16)v;
    }
  }
}

// ---------------------------------------------------------------------------
// NHWC relayout: x[b][c][h][w] f32 -> xT[b][h][w][c] bf16 (validated).
// ---------------------------------------------------------------------------
__global__ __launch_bounds__(256) void nhwc_kernel(const float* __restrict__ x,
                                                   __bf16* __restrict__ xT) {
  int tid = blockIdx.x * 256 + threadIdx.x;
  int b = tid >> 14, pix = tid & (HW - 1);
  const float* xp = x + (size_t)b * CIN * HW + pix;
  __bf16* op = xT + (size_t)tid * CIN;
#pragma unroll
  for (int c0 = 0; c0 < CIN; c0 += 8) {
    bf16x8 v;
#pragma unroll
    for (int j = 0; j < 8; ++j) v[j] = (__bf16)xp[(size_t)(c0 + j) * HW];
    *(bf16x8*)(op + c0) = v;
  }
}

// ---------------------------------------------------------------------------
// Kernel A v2: offset/mask conv as bf16 MFMA GEMM over NHWC xT.
// Block = 64 pixels x 4 waves; wave wv owns pixels wv*16..+16, all 32 (27)
// outputs: 2 n-tiles. K = 9 taps x 3 K-steps of 32 channels.
// A-frag = the 16B dwordx4 load itself (NHWC, no bilinear). OOB taps return
// 0 via SRSRC bounds check (num_records = HW*192). Depth-2 tap pipeline,
// counted vmcnt(3); all in-loop vmem is volatile asm. Waves independent,
// no LDS -> race-free.
// ---------------------------------------------------------------------------
#define OISS_TAP(TAP, G) {                                                    \
    int ki = (TAP) / 3, kj = (TAP) % 3;                                       \
    int yy = h + ki - 1, xx = wg + kj - 1;                                    \
    bool ok = ((unsigned)yy < (unsigned)H) && ((unsigned)xx < (unsigned)W);   \
    unsigned vo = ok ? (unsigned)((yy * W + xx) * 192) + choff : 0x7f000000u; \
    asm volatile("buffer_load_dwordx4 %0, %1, %2, %3 offen"                   \
                 : "=v"(G[0]) : "v"(vo), "s"(rsrcX), "s"(0));                 \
    asm volatile("buffer_load_dwordx4 %0, %1, %2, %3 offen"                   \
                 : "=v"(G[1]) : "v"(vo), "s"(rsrcX), "s"(64));                \
    asm volatile("buffer_load_dwordx4 %0, %1, %2, %3 offen"                   \
                 : "=v"(G[2]) : "v"(vo), "s"(rsrcX), "s"(128));               \
  }

#define OISS_B(TAP)                                                           \
  _Pragma("unroll") for (int s = 0; s < 3; ++s)                               \
  _Pragma("unroll") for (int nt = 0; nt < 2; ++nt)                            \
    asm volatile("buffer_load_dwordx4 %0, %1, %2, %3 offen"                   \
                 : "=v"(bb[s * 2 + nt])                                       \
                 : "v"(voffB), "s"(rsrcW),                                    \
                   "s"((TAP) * 6144 + s * 2048 + nt * 1024));

#define OCOMP(GC)                                                             \
  _Pragma("unroll") for (int s = 0; s < 3; ++s) {                             \
    bf16x8 a = __builtin_bit_cast(bf16x8, GC[s]);                             \
    acc[0] = __builtin_amdgcn_mfma_f32_16x16x32_bf16(                         \
        a, __builtin_bit_cast(bf16x8, bb[s * 2 + 0]), acc[0], 0, 0, 0);       \
    acc[1] = __builtin_amdgcn_mfma_f32_16x16x32_bf16(                         \
        a, __builtin_bit_cast(bf16x8, bb[s * 2 + 1]), acc[1], 0, 0, 0);       \
  }

__global__ __launch_bounds__(256) void offmask_mfma(
    const __bf16* __restrict__ xT, const __bf16* __restrict__ wOT,
    const float* __restrict__ offset_b, const float* __restrict__ mask_b,
    float* __restrict__ offm) {
  int t = threadIdx.x;
  int lane = t & 63;
  int wv = __builtin_amdgcn_readfirstlane(t >> 6);
  int ln15 = lane & 15;

  int bid = (int)blockIdx.x;
  int nb = (bid & 7) * 512 + (bid >> 3);
  int b = nb >> 8;
  int rem = nb & 255;
  int h = rem >> 1;
  int w0 = (rem & 1) << 6;

  int pl = (wv << 4) + ln15;
  int wg = w0 + pl;
  unsigned choff = (unsigned)((lane >> 4) << 4);

  const __bf16* xb = xT + (size_t)b * HW * CIN;

  unsigned long long ba = (unsigned long long)(const void*)xb;
  u32x4 rsrcX;
  rsrcX.x = (unsigned)ba; rsrcX.y = (unsigned)(ba >> 32);
  rsrcX.z = (unsigned)(HW * 192);   // bounds check: OOB voff -> returns 0
  rsrcX.w = 0x00020000u;
  unsigned long long bwo = (unsigned long long)(const void*)wOT;
  u32x4 rsrcW;
  rsrcW.x = (unsigned)bwo; rsrcW.y = (unsigned)(bwo >> 32);
  rsrcW.z = (unsigned)(NOT * 2);
  rsrcW.w = 0x00020000u;
  unsigned voffB = (unsigned)(ln15 * 64 + ((lane >> 4) << 4));

  f32x4 acc[2];
  acc[0] = (f32x4){0.f, 0.f, 0.f, 0.f};
  acc[1] = (f32x4){0.f, 0.f, 0.f, 0.f};

  u32x4 gA[3], gB[3], bb[6];

  OISS_TAP(0, gA);
#pragma unroll
  for (int tap = 0; tap < 9; ++tap) {
    OISS_B(tap);                               // B(k): 6 loads
    if (tap < 8) {                             // A(k+1): 3 loads
      if (tap & 1) { OISS_TAP(tap + 1, gA); } else { OISS_TAP(tap + 1, gB); }
      asm volatile("s_waitcnt vmcnt(3)" ::: "memory");   // A(k)+B(k) done
    } else {
      asm volatile("s_waitcnt vmcnt(0)" ::: "memory");
    }
    __builtin_amdgcn_sched_barrier(0);         // rule #18
    if (tap & 1) { OCOMP(gB); } else { OCOMP(gA); }
  }

  // epilogue: D row = pixel, col = output o (validated layout)
  float* ob = offm + (size_t)b * 27 * HW + (size_t)h * W;
  int prow = w0 + (wv << 4) + ((lane >> 4) << 2);
  {
    float bv = offset_b[ln15];                 // nt0: o = 0..15, no sigmoid
    float4 o4;
    o4.x = acc[0][0] + bv; o4.y = acc[0][1] + bv;
    o4.z = acc[0][2] + bv; o4.w = acc[0][3] + bv;
    *(float4*)(ob + (size_t)ln15 * HW + prow) = o4;
  }
  if (ln15 < 11) {                             // nt1: o = 16..26
    int o = 16 + ln15;
    bool sig = (o >= 18);
    float bv = sig ? mask_b[o - 18] : offset_b[o];
    float4 o4;
    float v0 = acc[1][0] + bv, v1 = acc[1][1] + bv;
    float v2 = acc[1][2] + bv, v3 = acc[1][3] + bv;
    if (sig) {
      v0 = 1.f / (1.f + expf(-v0)); v1 = 1.f / (1.f + expf(-v1));
      v2 = 1.f / (1.f + expf(-v2)); v3 = 1.f / (1.f + expf(-v3));
    }
    o4.x = v0; o4.y = v1; o4.z = v2; o4.w = v3;
    *(float4*)(ob + (size_t)o * HW + prow) = o4;
  }
}

// ---------------------------------------------------------------------------
// Kernel B v9 (VALIDATED R9 — unchanged): NHWC register-gather deform conv,
// B-weights DMA'd per-tap into LDS, __syncthreads-protected.
// ---------------------------------------------------------------------------
#define GISS(K, G, WD) {                                                      \
    float dyv = offt[2 * (K)][pl];                                            \
    float dxv = offt[2 * (K) + 1][pl];                                        \
    float mv  = offt[18 + (K)][pl];                                           \
    int ki = (K) / 3, kj = (K) % 3;                                           \
    float py = (float)(h - 1 + ki) + dyv;                                     \
    float px = (float)(wg - 1 + kj) + dxv;                                    \
    float fy = floorf(py), fx = floorf(px);                                   \
    float wyf = py - fy, wxf = px - fx;                                       \
    int iy0 = (int)fy, ix0 = (int)fx;                                         \
    int iy1 = iy0 + 1, ix1 = ix0 + 1;                                         \
    bool y0ok = (unsigned)iy0 < (unsigned)H;                                  \
    bool y1ok = (unsigned)iy1 < (unsigned)H;                                  \
    bool x0ok = (unsigned)ix0 < (unsigned)W;                                  \
    bool x1ok = (unsigned)ix1 < (unsigned)W;                                  \
    WD[0] = (y0ok && x0ok) ? (1.f - wyf) * (1.f - wxf) * mv : 0.f;            \
    WD[1] = (y0ok && x1ok) ? (1.f - wyf) * wxf * mv : 0.f;                    \
    WD[2] = (y1ok && x0ok) ? wyf * (1.f - wxf) * mv : 0.f;                    \
    WD[3] = (y1ok && x1ok) ? wyf * wxf * mv : 0.f;                            \
    int cy0 = min(max(iy0, 0), H - 1), cy1 = min(max(iy1, 0), H - 1);         \
    int cx0 = min(max(ix0, 0), W - 1), cx1 = min(max(ix1, 0), W - 1);         \
    unsigned v00 = (unsigned)((cy0 * W + cx0) * 192) + choff;                 \
    unsigned v01 = (unsigned)((cy0 * W + cx1) * 192) + choff;                 \
    unsigned v10 = (unsigned)((cy1 * W + cx0) * 192) + choff;                 \
    unsigned v11 = (unsigned)((cy1 * W + cx1) * 192) + choff;                 \
    _Pragma("unroll") for (int ks = 0; ks < 3; ++ks) {                        \
      asm volatile("buffer_load_dwordx4 %0, %1, %2, %3 offen"                 \
                   : "=v"(G[ks * 4 + 0]) : "v"(v00), "s"(rsrcX), "s"(ks * 64)); \
      asm volatile("buffer_load_dwordx4 %0, %1, %2, %3 offen"                 \
                   : "=v"(G[ks * 4 + 1]) : "v"(v01), "s"(rsrcX), "s"(ks * 64)); \
      asm volatile("buffer_load_dwordx4 %0, %1, %2, %3 offen"                 \
                   : "=v"(G[ks * 4 + 2]) : "v"(v10), "s"(rsrcX), "s"(ks * 64)); \
      asm volatile("buffer_load_dwordx4 %0, %1, %2, %3 offen"                 \
                   : "=v"(G[ks * 4 + 3]) : "v"(v11), "s"(rsrcX), "s"(ks * 64)); \
    } }

#define COMBINE_KS(G, KS, WV, AF)                                             \
  _Pragma("unroll") for (int j = 0; j < 8; ++j) {                             \
    unsigned d00 = G[(KS) * 4 + 0][j >> 1], d01 = G[(KS) * 4 + 1][j >> 1];    \
    unsigned d10 = G[(KS) * 4 + 2][j >> 1], d11 = G[(KS) * 4 + 3][j >> 1];    \
    float v00 = (j & 1) ? bfhi(d00) : bflo(d00);                              \
    float v01 = (j & 1) ? bfhi(d01) : bflo(d01);                              \
    float v10 = (j & 1) ? bfhi(d10) : bflo(d10);                              \
    float v11 = (j & 1) ? bfhi(d11) : bflo(d11);                              \
    AF[j] = (__bf16)(WV[0] * v00 + WV[1] * v01 + WV[2] * v10 + WV[3] * v11);  \
  }

__global__ __launch_bounds__(256, 3) void deform_kernel(
    const __bf16* __restrict__ xT, const float* __restrict__ offm,
    const __bf16* __restrict__ wBTp, const float* __restrict__ bias,
    float* __restrict__ out) {
  __shared__ alignas(16) __bf16 Blds[BSTG];
  __shared__ float offt[27][64];

  int t = threadIdx.x;
  int lane = t & 63;
  int wv = __builtin_amdgcn_readfirstlane(t >> 6);
  int ln15 = lane & 15;

  int bid = (int)blockIdx.x;
  int nb = (bid & 7) * 512 + (bid >> 3);
  int b = nb >> 8;
  int rem = nb & 255;
  int h = rem >> 1;
  int w0 = (rem & 1) << 6;

  int pl = (wv << 4) + ln15;
  int wg = w0 + pl;
  unsigned choff = (unsigned)((lane >> 4) << 4);

  const __bf16* xb = xT + (size_t)b * HW * CIN;
  const float* ob = offm + (size_t)b * 27 * HW;

  unsigned long long ba = (unsigned long long)(const void*)xb;
  u32x4 rsrcX;
  rsrcX.x = (unsigned)ba; rsrcX.y = (unsigned)(ba >> 32);
  rsrcX.z = 0xffffffffu;  rsrcX.w = 0x00020000u;

  for (int e = t; e < 27 * 64; e += 256) {
    int o = e >> 6, p = e & 63;
    offt[o][p] = ob[(size_t)o * HW + (size_t)h * W + w0 + p];
  }
  __syncthreads();

  f32x4 acc[6];
#pragma unroll
  for (int nt = 0; nt < 6; ++nt) acc[nt] = (f32x4){0.f, 0.f, 0.f, 0.f};

  u32x4 g[12];
  f32x4 wd;
  const __bf16* bfrag = Blds + (size_t)ln15 * BPITCH + ((lane >> 4) << 3);

  for (int k = 0; k < 9; ++k) {
    {
      const __bf16* src = wBTp + (size_t)k * BTAP + (size_t)wv * 2560 + (size_t)lane * 8;
      __bf16* dst = Blds + wv * 2560;
#pragma unroll
      for (int q = 0; q < 5; ++q)
        GLDS16(src + q * 512, dst + q * 512);
    }

    GISS(k, g, wd);

    asm volatile("s_waitcnt vmcnt(0)" ::: "memory");
    __builtin_amdgcn_sched_barrier(0);

    bf16x8 af0, af1, af2;
    COMBINE_KS(g, 0, wd, af0);
    COMBINE_KS(g, 1, wd, af1);
    COMBINE_KS(g, 2, wd, af2);

    __syncthreads();

#pragma unroll
    for (int nt = 0; nt < 6; ++nt) {
      const __bf16* bp = bfrag + nt * 16 * BPITCH;
      bf16x8 b0 = *(const bf16x8*)(bp);
      bf16x8 b1 = *(const bf16x8*)(bp + 32);
      bf16x8 b2 = *(const bf16x8*)(bp + 64);
      acc[nt] = __builtin_amdgcn_mfma_f32_16x16x32_bf16(af0, b0, acc[nt], 0, 0, 0);
      acc[nt] = __builtin_amdgcn_mfma_f32_16x16x32_bf16(af1, b1, acc[nt], 0, 0, 0);
      acc[nt] = __builtin_amdgcn_mfma_f32_16x16x32_bf16(af2, b2, acc[nt], 0, 0, 0);
    }

    __syncthreads();
  }

  float* outb = out + (size_t)b * COUT * HW + (size_t)h * W;
  int prow = w0 + (wv << 4) + ((lane >> 4) << 2);
#pragma unroll
  for (int nt = 0; nt < 6; ++nt) {
    int ch = nt * 16 + ln15;
    float bv = bias[ch];
    float4 o4;
    o4.x = acc[nt][0] + bv;
    o4.y = acc[nt][1] + bv;
    o4.z = acc[nt][2] + bv;
    o4.w = acc[nt][3] + bv;
    *(float4*)(outb + (size_t)ch * HW + prow) = o4;
  }
}

// ---------------------------------------------------------------------------
extern "C" void kernel_launch(void* const* d_in, const int* in_sizes, int n_in,
                              void* d_out, int out_size, void* d_ws, size_t ws_size,
                              hipStream_t stream) {
  const float* x        = (const float*)d_in[0];
  const float* weight   = (const float*)d_in[1];
  const float* bias     = (const float*)d_in[2];
  const float* offset_w = (const float*)d_in[3];
  const float* offset_b = (const float*)d_in[4];
  const float* mask_w   = (const float*)d_in[5];
  const float* mask_b   = (const float*)d_in[6];
  float* out = (float*)d_out;

  __bf16* xT   = (__bf16*)d_ws;                              // NPIX*96 bf16
  float*  offm = (float*)(xT + (size_t)NPIX * CIN);          // 16*27*16384 f32
  __bf16* wOT  = (__bf16*)(offm + (size_t)BATCH * 27 * HW);  // 27648 bf16
  __bf16* wBTp = wOT + NOT;                                  // 9*9984 + 256 bf16

  const int nPrep = NOT + 9 * BTAP + 256;
  prep_weights<<<(nPrep + 255) / 256, 256, 0, stream>>>(weight, offset_w, mask_w, wOT, wBTp);
  nhwc_kernel<<<NPIX / 256, 256, 0, stream>>>(x, xT);
  offmask_mfma<<<BATCH * H * (W / 64), 256, 0, stream>>>(xT, wOT, offset_b, mask_b, offm);
  deform_kernel<<<BATCH * H * (W / 64), 256, 0, stream>>>(xT, offm, wBTp, bias, out);
}

// Round 11
// 284.141 us; speedup vs baseline: 2.8869x; 1.0044x over previous
//
#include <hip/hip_runtime.h>
#include <math.h>

#define W 128
#define H 128
#define HW 16384
#define CIN 96
#define COUT 96
#define BATCH 16
#define NPIX (BATCH * HW)
#define BPITCH 104                 // padded B row pitch (bf16): 52 dwords -> <=2-way banks
#define BTAP (COUT * BPITCH)       // 9984 elems per tap image
#define BSTG 10240                 // LDS B buffer elems (20480 B, covers DMA overshoot)
#define NOT (27 * 32 * 32)         // wOT elems: 27 K-steps x 32 out x 32 k

typedef __bf16 bf16x8 __attribute__((ext_vector_type(8)));
typedef float f32x4 __attribute__((ext_vector_type(4)));
typedef unsigned int u32x4 __attribute__((ext_vector_type(4)));

typedef const unsigned int __attribute__((address_space(1))) gu32;
typedef unsigned int __attribute__((address_space(3))) lu32;
#define GLDS16(g, l) __builtin_amdgcn_global_load_lds((gu32*)(g), (lu32*)(l), 16, 0, 0)

__device__ inline float bflo(unsigned d) { union { unsigned u; float f; } t; t.u = d << 16; return t.f; }
__device__ inline float bfhi(unsigned d) { union { unsigned u; float f; } t; t.u = d & 0xffff0000u; return t.f; }

// ---------------------------------------------------------------------------
// Weight prep (R10-validated):
//   wOT[ks][o(32,pad)][c(32)] bf16: offset/mask weights as MFMA B-tiles
//   wBTp[tap][o][104] bf16: padded deform weights for LDS DMA.
// ---------------------------------------------------------------------------
__global__ void prep_weights(const float* __restrict__ weight,
                             const float* __restrict__ offset_w,
                             const float* __restrict__ mask_w,
                             __bf16* __restrict__ wOT,
                             __bf16* __restrict__ wBTp) {
  int idx = blockIdx.x * blockDim.x + threadIdx.x;
  if (idx < NOT) {
    int c = idx & 31;
    int o = (idx >> 5) & 31;
    int ks = idx >> 10;
    int tap = ks / 3;
    int cg = (ks % 3) * 32 + c;
    float v = 0.f;
    if (o < 18)      v = offset_w[(o * CIN + cg) * 9 + tap];
    else if (o < 27) v = mask_w[((o - 18) * CIN + cg) * 9 + tap];
    wOT[idx] = (__bf16)v;
  } else {
    int j = idx - NOT;
    if (j < 9 * BTAP + 256) {
      int c = j % BPITCH;
      int o = (j / BPITCH) % COUT;
      int tap = j / BTAP;
      float v = 0.f;
      if (tap < 9 && c < CIN) v = weight[(o * CIN + c) * 9 + tap];
      wBTp[j] = (__bf16)v;
    }
  }
}

// ---------------------------------------------------------------------------
// NHWC relayout: x[b][c][h][w] f32 -> xT[b][h][w][c] bf16 (validated).
// ---------------------------------------------------------------------------
__global__ __launch_bounds__(256) void nhwc_kernel(const float* __restrict__ x,
                                                   __bf16* __restrict__ xT) {
  int tid = blockIdx.x * 256 + threadIdx.x;
  int b = tid >> 14, pix = tid & (HW - 1);
  const float* xp = x + (size_t)b * CIN * HW + pix;
  __bf16* op = xT + (size_t)tid * CIN;
#pragma unroll
  for (int c0 = 0; c0 < CIN; c0 += 8) {
    bf16x8 v;
#pragma unroll
    for (int j = 0; j < 8; ++j) v[j] = (__bf16)xp[(size_t)(c0 + j) * HW];
    *(bf16x8*)(op + c0) = v;
  }
}

// ---------------------------------------------------------------------------
// Kernel A v2 (R10-validated, unchanged): offset/mask conv as bf16 MFMA GEMM.
// ---------------------------------------------------------------------------
#define OISS_TAP(TAP, G) {                                                    \
    int ki = (TAP) / 3, kj = (TAP) % 3;                                       \
    int yy = h + ki - 1, xx = wg + kj - 1;                                    \
    bool ok = ((unsigned)yy < (unsigned)H) && ((unsigned)xx < (unsigned)W);   \
    unsigned vo = ok ? (unsigned)((yy * W + xx) * 192) + choff : 0x7f000000u; \
    asm volatile("buffer_load_dwordx4 %0, %1, %2, %3 offen"                   \
                 : "=v"(G[0]) : "v"(vo), "s"(rsrcX), "s"(0));                 \
    asm volatile("buffer_load_dwordx4 %0, %1, %2, %3 offen"                   \
                 : "=v"(G[1]) : "v"(vo), "s"(rsrcX), "s"(64));                \
    asm volatile("buffer_load_dwordx4 %0, %1, %2, %3 offen"                   \
                 : "=v"(G[2]) : "v"(vo), "s"(rsrcX), "s"(128));               \
  }

#define OISS_B(TAP)                                                           \
  _Pragma("unroll") for (int s = 0; s < 3; ++s)                               \
  _Pragma("unroll") for (int nt = 0; nt < 2; ++nt)                            \
    asm volatile("buffer_load_dwordx4 %0, %1, %2, %3 offen"                   \
                 : "=v"(bb[s * 2 + nt])                                       \
                 : "v"(voffB), "s"(rsrcW),                                    \
                   "s"((TAP) * 6144 + s * 2048 + nt * 1024));

#define OCOMP(GC)                                                             \
  _Pragma("unroll") for (int s = 0; s < 3; ++s) {                             \
    bf16x8 a = __builtin_bit_cast(bf16x8, GC[s]);                             \
    acc[0] = __builtin_amdgcn_mfma_f32_16x16x32_bf16(                         \
        a, __builtin_bit_cast(bf16x8, bb[s * 2 + 0]), acc[0], 0, 0, 0);       \
    acc[1] = __builtin_amdgcn_mfma_f32_16x16x32_bf16(                         \
        a, __builtin_bit_cast(bf16x8, bb[s * 2 + 1]), acc[1], 0, 0, 0);       \
  }

__global__ __launch_bounds__(256) void offmask_mfma(
    const __bf16* __restrict__ xT, const __bf16* __restrict__ wOT,
    const float* __restrict__ offset_b, const float* __restrict__ mask_b,
    float* __restrict__ offm) {
  int t = threadIdx.x;
  int lane = t & 63;
  int wv = __builtin_amdgcn_readfirstlane(t >> 6);
  int ln15 = lane & 15;

  int bid = (int)blockIdx.x;
  int nb = (bid & 7) * 512 + (bid >> 3);
  int b = nb >> 8;
  int rem = nb & 255;
  int h = rem >> 1;
  int w0 = (rem & 1) << 6;

  int pl = (wv << 4) + ln15;
  int wg = w0 + pl;
  unsigned choff = (unsigned)((lane >> 4) << 4);

  const __bf16* xb = xT + (size_t)b * HW * CIN;

  unsigned long long ba = (unsigned long long)(const void*)xb;
  u32x4 rsrcX;
  rsrcX.x = (unsigned)ba; rsrcX.y = (unsigned)(ba >> 32);
  rsrcX.z = (unsigned)(HW * 192);
  rsrcX.w = 0x00020000u;
  unsigned long long bwo = (unsigned long long)(const void*)wOT;
  u32x4 rsrcW;
  rsrcW.x = (unsigned)bwo; rsrcW.y = (unsigned)(bwo >> 32);
  rsrcW.z = (unsigned)(NOT * 2);
  rsrcW.w = 0x00020000u;
  unsigned voffB = (unsigned)(ln15 * 64 + ((lane >> 4) << 4));

  f32x4 acc[2];
  acc[0] = (f32x4){0.f, 0.f, 0.f, 0.f};
  acc[1] = (f32x4){0.f, 0.f, 0.f, 0.f};

  u32x4 gA[3], gB[3], bb[6];

  OISS_TAP(0, gA);
#pragma unroll
  for (int tap = 0; tap < 9; ++tap) {
    OISS_B(tap);
    if (tap < 8) {
      if (tap & 1) { OISS_TAP(tap + 1, gA); } else { OISS_TAP(tap + 1, gB); }
      asm volatile("s_waitcnt vmcnt(3)" ::: "memory");
    } else {
      asm volatile("s_waitcnt vmcnt(0)" ::: "memory");
    }
    __builtin_amdgcn_sched_barrier(0);
    if (tap & 1) { OCOMP(gB); } else { OCOMP(gA); }
  }

  float* ob = offm + (size_t)b * 27 * HW + (size_t)h * W;
  int prow = w0 + (wv << 4) + ((lane >> 4) << 2);
  {
    float bv = offset_b[ln15];
    float4 o4;
    o4.x = acc[0][0] + bv; o4.y = acc[0][1] + bv;
    o4.z = acc[0][2] + bv; o4.w = acc[0][3] + bv;
    *(float4*)(ob + (size_t)ln15 * HW + prow) = o4;
  }
  if (ln15 < 11) {
    int o = 16 + ln15;
    bool sig = (o >= 18);
    float bv = sig ? mask_b[o - 18] : offset_b[o];
    float4 o4;
    float v0 = acc[1][0] + bv, v1 = acc[1][1] + bv;
    float v2 = acc[1][2] + bv, v3 = acc[1][3] + bv;
    if (sig) {
      v0 = 1.f / (1.f + expf(-v0)); v1 = 1.f / (1.f + expf(-v1));
      v2 = 1.f / (1.f + expf(-v2)); v3 = 1.f / (1.f + expf(-v3));
    }
    o4.x = v0; o4.y = v1; o4.z = v2; o4.w = v3;
    *(float4*)(ob + (size_t)o * HW + prow) = o4;
  }
}

// ---------------------------------------------------------------------------
// Kernel B v10: R9 skeleton with ROTATED tap loop.
// Steady state per tap (vmem queue at entry: [G(k) x12, DMA(k) x5]):
//   vmcnt(5)          -> G(k) landed (own DMA may still fly)
//   COMBINE(k)        -> A-frags
//   __syncthreads     -> drains own DMA; barrier => ALL waves' DMA landed
//   GISS(k+1)         -> next gathers fly across MFMA + sync2
//   MFMA(k)           -> reads Blds (lgkm pipe, independent of vmcnt)
//   __syncthreads     -> all readers done (drains G(k+1): overlapped w/ MFMA)
//   STAGE_B(k+1)      -> DMA into Blds (safe: after sync2, R9-identical)
// Same barrier protocol class as R9 (__syncthreads-drain only, no raw
// barriers); only the ISSUE POINTS moved earlier. No new LDS/registers.
// ---------------------------------------------------------------------------
#define GISS(K, G, WD) {                                                      \
    float dyv = offt[2 * (K)][pl];                                            \
    float dxv = offt[2 * (K) + 1][pl];                                        \
    float mv  = offt[18 + (K)][pl];                                           \
    int ki = (K) / 3, kj = (K) % 3;                                           \
    float py = (float)(h - 1 + ki) + dyv;                                     \
    float px = (float)(wg - 1 + kj) + dxv;                                    \
    float fy = floorf(py), fx = floorf(px);                                   \
    float wyf = py - fy, wxf = px - fx;                                       \
    int iy0 = (int)fy, ix0 = (int)fx;                                         \
    int iy1 = iy0 + 1, ix1 = ix0 + 1;                                         \
    bool y0ok = (unsigned)iy0 < (unsigned)H;                                  \
    bool y1ok = (unsigned)iy1 < (unsigned)H;                                  \
    bool x0ok = (unsigned)ix0 < (unsigned)W;                                  \
    bool x1ok = (unsigned)ix1 < (unsigned)W;                                  \
    WD[0] = (y0ok && x0ok) ? (1.f - wyf) * (1.f - wxf) * mv : 0.f;            \
    WD[1] = (y0ok && x1ok) ? (1.f - wyf) * wxf * mv : 0.f;                    \
    WD[2] = (y1ok && x0ok) ? wyf * (1.f - wxf) * mv : 0.f;                    \
    WD[3] = (y1ok && x1ok) ? wyf * wxf * mv : 0.f;                            \
    int cy0 = min(max(iy0, 0), H - 1), cy1 = min(max(iy1, 0), H - 1);         \
    int cx0 = min(max(ix0, 0), W - 1), cx1 = min(max(ix1, 0), W - 1);         \
    unsigned v00 = (unsigned)((cy0 * W + cx0) * 192) + choff;                 \
    unsigned v01 = (unsigned)((cy0 * W + cx1) * 192) + choff;                 \
    unsigned v10 = (unsigned)((cy1 * W + cx0) * 192) + choff;                 \
    unsigned v11 = (unsigned)((cy1 * W + cx1) * 192) + choff;                 \
    _Pragma("unroll") for (int ks = 0; ks < 3; ++ks) {                        \
      asm volatile("buffer_load_dwordx4 %0, %1, %2, %3 offen"                 \
                   : "=v"(G[ks * 4 + 0]) : "v"(v00), "s"(rsrcX), "s"(ks * 64)); \
      asm volatile("buffer_load_dwordx4 %0, %1, %2, %3 offen"                 \
                   : "=v"(G[ks * 4 + 1]) : "v"(v01), "s"(rsrcX), "s"(ks * 64)); \
      asm volatile("buffer_load_dwordx4 %0, %1, %2, %3 offen"                 \
                   : "=v"(G[ks * 4 + 2]) : "v"(v10), "s"(rsrcX), "s"(ks * 64)); \
      asm volatile("buffer_load_dwordx4 %0, %1, %2, %3 offen"                 \
                   : "=v"(G[ks * 4 + 3]) : "v"(v11), "s"(rsrcX), "s"(ks * 64)); \
    } }

#define COMBINE_KS(G, KS, WV, AF)                                             \
  _Pragma("unroll") for (int j = 0; j < 8; ++j) {                             \
    unsigned d00 = G[(KS) * 4 + 0][j >> 1], d01 = G[(KS) * 4 + 1][j >> 1];    \
    unsigned d10 = G[(KS) * 4 + 2][j >> 1], d11 = G[(KS) * 4 + 3][j >> 1];    \
    float v00 = (j & 1) ? bfhi(d00) : bflo(d00);                              \
    float v01 = (j & 1) ? bfhi(d01) : bflo(d01);                              \
    float v10 = (j & 1) ? bfhi(d10) : bflo(d10);                              \
    float v11 = (j & 1) ? bfhi(d11) : bflo(d11);                              \
    AF[j] = (__bf16)(WV[0] * v00 + WV[1] * v01 + WV[2] * v10 + WV[3] * v11);  \
  }

#define STAGE_B(K) {                                                          \
    const __bf16* src = wBTp + (size_t)(K) * BTAP + (size_t)wv * 2560 +       \
                        (size_t)lane * 8;                                     \
    __bf16* dst = Blds + wv * 2560;                                           \
    _Pragma("unroll") for (int q = 0; q < 5; ++q)                             \
      GLDS16(src + q * 512, dst + q * 512);                                   \
  }

__global__ __launch_bounds__(256, 3) void deform_kernel(
    const __bf16* __restrict__ xT, const float* __restrict__ offm,
    const __bf16* __restrict__ wBTp, const float* __restrict__ bias,
    float* __restrict__ out) {
  __shared__ alignas(16) __bf16 Blds[BSTG];
  __shared__ float offt[27][64];

  int t = threadIdx.x;
  int lane = t & 63;
  int wv = __builtin_amdgcn_readfirstlane(t >> 6);
  int ln15 = lane & 15;

  int bid = (int)blockIdx.x;
  int nb = (bid & 7) * 512 + (bid >> 3);
  int b = nb >> 8;
  int rem = nb & 255;
  int h = rem >> 1;
  int w0 = (rem & 1) << 6;

  int pl = (wv << 4) + ln15;
  int wg = w0 + pl;
  unsigned choff = (unsigned)((lane >> 4) << 4);

  const __bf16* xb = xT + (size_t)b * HW * CIN;
  const float* ob = offm + (size_t)b * 27 * HW;

  unsigned long long ba = (unsigned long long)(const void*)xb;
  u32x4 rsrcX;
  rsrcX.x = (unsigned)ba; rsrcX.y = (unsigned)(ba >> 32);
  rsrcX.z = 0xffffffffu;  rsrcX.w = 0x00020000u;

  for (int e = t; e < 27 * 64; e += 256) {
    int o = e >> 6, p = e & 63;
    offt[o][p] = ob[(size_t)o * HW + (size_t)h * W + w0 + p];
  }
  __syncthreads();

  f32x4 acc[6];
#pragma unroll
  for (int nt = 0; nt < 6; ++nt) acc[nt] = (f32x4){0.f, 0.f, 0.f, 0.f};

  u32x4 g[12];
  f32x4 wd;
  const __bf16* bfrag = Blds + (size_t)ln15 * BPITCH + ((lane >> 4) << 3);

  // prologue: establish steady-state queue [G(0) x12, DMA(0) x5]
  GISS(0, g, wd);
  STAGE_B(0);

  for (int k = 0; k < 9; ++k) {
    // G(k) complete at vmcnt(5); own DMA(k) may still be in flight
    asm volatile("s_waitcnt vmcnt(5)" ::: "memory");
    __builtin_amdgcn_sched_barrier(0);          // rule #18

    bf16x8 af0, af1, af2;
    COMBINE_KS(g, 0, wd, af0);
    COMBINE_KS(g, 1, wd, af1);
    COMBINE_KS(g, 2, wd, af2);

    __syncthreads();   // drains own DMA(k); barrier => Blds[k] valid

    if (k < 8) { GISS(k + 1, g, wd); }   // fly across MFMA + sync2

#pragma unroll
    for (int nt = 0; nt < 6; ++nt) {
      const __bf16* bp = bfrag + nt * 16 * BPITCH;
      bf16x8 b0 = *(const bf16x8*)(bp);
      bf16x8 b1 = *(const bf16x8*)(bp + 32);
      bf16x8 b2 = *(const bf16x8*)(bp + 64);
      acc[nt] = __builtin_amdgcn_mfma_f32_16x16x32_bf16(af0, b0, acc[nt], 0, 0, 0);
      acc[nt] = __builtin_amdgcn_mfma_f32_16x16x32_bf16(af1, b1, acc[nt], 0, 0, 0);
      acc[nt] = __builtin_amdgcn_mfma_f32_16x16x32_bf16(af2, b2, acc[nt], 0, 0, 0);
    }

    if (k < 8) {
      __syncthreads();   // readers done (drains G(k+1), overlapped w/ MFMA)
      STAGE_B(k + 1);    // DMA into Blds, post-barrier (R9-identical)
    }
  }

  float* outb = out + (size_t)b * COUT * HW + (size_t)h * W;
  int prow = w0 + (wv << 4) + ((lane >> 4) << 2);
#pragma unroll
  for (int nt = 0; nt < 6; ++nt) {
    int ch = nt * 16 + ln15;
    float bv = bias[ch];
    float4 o4;
    o4.x = acc[nt][0] + bv;
    o4.y = acc[nt][1] + bv;
    o4.z = acc[nt][2] + bv;
    o4.w = acc[nt][3] + bv;
    *(float4*)(outb + (size_t)ch * HW + prow) = o4;
  }
}

// ---------------------------------------------------------------------------
extern "C" void kernel_launch(void* const* d_in, const int* in_sizes, int n_in,
                              void* d_out, int out_size, void* d_ws, size_t ws_size,
                              hipStream_t stream) {
  const float* x        = (const float*)d_in[0];
  const float* weight   = (const float*)d_in[1];
  const float* bias     = (const float*)d_in[2];
  const float* offset_w = (const float*)d_in[3];
  const float* offset_b = (const float*)d_in[4];
  const float* mask_w   = (const float*)d_in[5];
  const float* mask_b   = (const float*)d_in[6];
  float* out = (float*)d_out;

  __bf16* xT   = (__bf16*)d_ws;                              // NPIX*96 bf16
  float*  offm = (float*)(xT + (size_t)NPIX * CIN);          // 16*27*16384 f32
  __bf16* wOT  = (__bf16*)(offm + (size_t)BATCH * 27 * HW);  // 27648 bf16
  __bf16* wBTp = wOT + NOT;                                  // 9*9984 + 256 bf16

  const int nPrep = NOT + 9 * BTAP + 256;
  prep_weights<<<(nPrep + 255) / 256, 256, 0, stream>>>(weight, offset_w, mask_w, wOT, wBTp);
  nhwc_kernel<<<NPIX / 256, 256, 0, stream>>>(x, xT);
  offmask_mfma<<<BATCH * H * (W / 64), 256, 0, stream>>>(xT, wOT, offset_b, mask_b, offm);
  deform_kernel<<<BATCH * H * (W / 64), 256, 0, stream>>>(xT, offm, wBTp, bias, out);
}